// Round 1
// baseline (171.152 us; speedup 1.0000x reference)
//
#include <hip/hip_runtime.h>
#include <hip/hip_bf16.h>

#define XLEN   262144
#define NT     513
#define TPAD   520
#define OUTKT  (2048 * 513)

typedef __attribute__((ext_vector_type(8))) short short8;
typedef __attribute__((ext_vector_type(4))) float f32x4;

__device__ __forceinline__ short cvt_bf16(float f) {
  return __builtin_bit_cast(short, (__bf16)f);
}

// ---------------- prep: fp32 weights -> bf16 in ws ----------------
__global__ __launch_bounds__(256) void conv_w_kernel(const float* __restrict__ src,
                                                     short* __restrict__ dst) {
  size_t i = ((size_t)blockIdx.x * 256 + threadIdx.x) * 8;
  f32x4 a = *(const f32x4*)(src + i);
  f32x4 b = *(const f32x4*)(src + i + 4);
  short8 o;
#pragma unroll
  for (int j = 0; j < 4; ++j) o[j] = cvt_bf16(a[j]);
#pragma unroll
  for (int j = 0; j < 4; ++j) o[4 + j] = cvt_bf16(b[j]);
  *(short8*)(dst + i) = o;
}

// ---------------- prep: reflect-padded frames -> bf16 in ws ----------------
__global__ __launch_bounds__(256) void conv_frames_kernel(const float* __restrict__ x,
                                                          short* __restrict__ fr) {
  int gid = blockIdx.x * 256 + threadIdx.x;  // one 8-sample chunk each
  int c  = (gid & 255) * 8;                  // 0..2040
  int bt = gid >> 8;                         // 0 .. 8*513-1
  int t  = bt % NT;
  int b  = bt / NT;
  const float* xb = x + (size_t)b * XLEN;
  int base = t * 512 + c - 1024;             // x-coordinate of first sample
  float v[8];
  if (base >= 0 && base + 7 < XLEN) {
    *(f32x4*)(v)     = *(const f32x4*)(xb + base);
    *(f32x4*)(v + 4) = *(const f32x4*)(xb + base + 4);
  } else {
#pragma unroll
    for (int j = 0; j < 8; ++j) {
      int m = base + j;
      m = (m < 0) ? -m : m;
      m = (m >= XLEN) ? (2 * XLEN - 2 - m) : m;
      v[j] = xb[m];
    }
  }
  short8 o;
#pragma unroll
  for (int j = 0; j < 8; ++j) o[j] = cvt_bf16(v[j]);
  *(short8*)&fr[(((size_t)(b * TPAD + t)) << 11) + c] = o;
}

// ---------------- main GEMM ----------------
// C_real[k,t] = sum_n wcos[k,n]*frames[t,n];  C_imag likewise with wsin.
// BM=128 (freq k), BN=128 (frames t), BK=64. 4 waves, each 64x64 per matrix.
__device__ __forceinline__ int swz(int r, int c) {
  // short-index swizzle: row stride 64 shorts (128B); XOR bits 3..5 with row&7
  return (r * 64 + c) ^ ((r & 7) << 3);
}

template <bool WS>
__global__ __launch_bounds__(256) void dft_gemm_kernel(
    const float* __restrict__ x,
    const float* __restrict__ wsin_f,
    const float* __restrict__ wcos_f,
    const short* __restrict__ wc_bf,
    const short* __restrict__ ws_bf,
    const short* __restrict__ fr_bf,
    float* __restrict__ outR,
    float* __restrict__ outI) {
  __shared__ short lwc[128 * 64];
  __shared__ short lws[128 * 64];
  __shared__ short lf [128 * 64];

  const int tid  = threadIdx.x;
  const int lane = tid & 63;
  const int wid  = tid >> 6;
  const int k0   = blockIdx.x * 128;
  const int t0   = blockIdx.y * 128;
  const int b    = blockIdx.z;
  const int wm   = (wid >> 1) * 64;
  const int wn   = (wid & 1) * 64;

  f32x4 accR[4][4], accI[4][4];
#pragma unroll
  for (int m = 0; m < 4; ++m)
#pragma unroll
    for (int n = 0; n < 4; ++n) {
      accR[m][n] = (f32x4)0.0f;
      accI[m][n] = (f32x4)0.0f;
    }

  const float* xb  = x + (size_t)b * XLEN;
  const short* frb = fr_bf + ((size_t)(b * TPAD) << 11);

  const int fr_r = lane & 15;        // fragment row (A) / col (B)
  const int fk   = (lane >> 4) * 8;  // k-offset within 32

  for (int n0 = 0; n0 < 2048; n0 += 64) {
    __syncthreads();
    // ---- stage 128x64 tiles of wcos, wsin, frames into LDS (bf16, swizzled) ----
#pragma unroll
    for (int i = 0; i < 4; ++i) {
      const int ch = tid + i * 256;   // 0..1023
      const int r  = ch >> 3;         // row 0..127
      const int c  = (ch & 7) * 8;    // col 0..56
      const int t  = t0 + r;
      short8 vc, vs, vf;
      if (WS) {
        vc = *(const short8*)&wc_bf[(((size_t)(k0 + r)) << 11) + n0 + c];
        vs = *(const short8*)&ws_bf[(((size_t)(k0 + r)) << 11) + n0 + c];
        if (t < NT) {
          vf = *(const short8*)&frb[(((size_t)t) << 11) + n0 + c];
        } else {
#pragma unroll
          for (int j = 0; j < 8; ++j) vf[j] = 0;
        }
      } else {
        const float* pc = wcos_f + (((size_t)(k0 + r)) << 11) + n0 + c;
        const float* ps = wsin_f + (((size_t)(k0 + r)) << 11) + n0 + c;
        f32x4 c0 = *(const f32x4*)pc, c1 = *(const f32x4*)(pc + 4);
        f32x4 s0 = *(const f32x4*)ps, s1 = *(const f32x4*)(ps + 4);
        float fv[8];
        if (t < NT) {
          int base = t * 512 + n0 + c - 1024;
          if (base >= 0 && base + 7 < XLEN) {
            *(f32x4*)(fv)     = *(const f32x4*)(xb + base);
            *(f32x4*)(fv + 4) = *(const f32x4*)(xb + base + 4);
          } else {
#pragma unroll
            for (int j = 0; j < 8; ++j) {
              int m = base + j;
              m = (m < 0) ? -m : m;
              m = (m >= XLEN) ? (2 * XLEN - 2 - m) : m;
              fv[j] = xb[m];
            }
          }
        } else {
#pragma unroll
          for (int j = 0; j < 8; ++j) fv[j] = 0.0f;
        }
#pragma unroll
        for (int j = 0; j < 4; ++j) { vc[j] = cvt_bf16(c0[j]); vc[4 + j] = cvt_bf16(c1[j]); }
#pragma unroll
        for (int j = 0; j < 4; ++j) { vs[j] = cvt_bf16(s0[j]); vs[4 + j] = cvt_bf16(s1[j]); }
#pragma unroll
        for (int j = 0; j < 8; ++j) vf[j] = cvt_bf16(fv[j]);
      }
      *(short8*)&lwc[swz(r, c)] = vc;
      *(short8*)&lws[swz(r, c)] = vs;
      *(short8*)&lf [swz(r, c)] = vf;
    }
    __syncthreads();
    // ---- compute: 2 k-substeps of 32; 16 MFMA per matrix per substep ----
#pragma unroll
    for (int ks = 0; ks < 2; ++ks) {
      const int kb = ks * 32 + fk;
      short8 a_c[4], a_s[4], b_f[4];
#pragma unroll
      for (int m = 0; m < 4; ++m)
        a_c[m] = *(const short8*)&lwc[swz(wm + m * 16 + fr_r, kb)];
#pragma unroll
      for (int m = 0; m < 4; ++m)
        a_s[m] = *(const short8*)&lws[swz(wm + m * 16 + fr_r, kb)];
#pragma unroll
      for (int n = 0; n < 4; ++n)
        b_f[n] = *(const short8*)&lf[swz(wn + n * 16 + fr_r, kb)];
#pragma unroll
      for (int m = 0; m < 4; ++m)
#pragma unroll
        for (int n = 0; n < 4; ++n) {
          accR[m][n] = __builtin_amdgcn_mfma_f32_16x16x32_bf16(a_c[m], b_f[n], accR[m][n], 0, 0, 0);
          accI[m][n] = __builtin_amdgcn_mfma_f32_16x16x32_bf16(a_s[m], b_f[n], accI[m][n], 0, 0, 0);
        }
    }
  }

  // ---- epilogue: C/D layout col=lane&15, row=(lane>>4)*4+reg ----
#pragma unroll
  for (int m = 0; m < 4; ++m) {
#pragma unroll
    for (int n = 0; n < 4; ++n) {
      const int row = k0 + wm + m * 16 + (lane >> 4) * 4;
      const int col = t0 + wn + n * 16 + (lane & 15);
      if (col < NT) {
        size_t base = (size_t)b * OUTKT + (size_t)row * NT + col;
#pragma unroll
        for (int r = 0; r < 4; ++r) {
          outR[base + (size_t)r * NT] = accR[m][n][r];
          outI[base + (size_t)r * NT] = -accI[m][n][r];
        }
      }
    }
  }
}

extern "C" void kernel_launch(void* const* d_in, const int* in_sizes, int n_in,
                              void* d_out, int out_size, void* d_ws, size_t ws_size,
                              hipStream_t stream) {
  const float* x    = (const float*)d_in[0];
  const float* wsin = (const float*)d_in[1];
  const float* wcos = (const float*)d_in[2];
  float* outR = (float*)d_out;
  float* outI = outR + (size_t)8 * OUTKT;

  short* wc_bf = (short*)d_ws;
  short* ws_bf = wc_bf + (size_t)2048 * 2048;
  short* fr_bf = ws_bf + (size_t)2048 * 2048;
  const size_t ws_need = ((size_t)2 * 2048 * 2048 + (size_t)8 * TPAD * 2048) * sizeof(short);

  dim3 grid(16, 5, 8);  // (freq tiles, frame tiles, batch)
  if (ws_size >= ws_need) {
    conv_w_kernel<<<2048, 256, 0, stream>>>(wcos, wc_bf);
    conv_w_kernel<<<2048, 256, 0, stream>>>(wsin, ws_bf);
    conv_frames_kernel<<<8 * NT, 256, 0, stream>>>(x, fr_bf);
    dft_gemm_kernel<true><<<grid, 256, 0, stream>>>(x, wsin, wcos, wc_bf, ws_bf, fr_bf, outR, outI);
  } else {
    dft_gemm_kernel<false><<<grid, 256, 0, stream>>>(x, wsin, wcos, wc_bf, ws_bf, fr_bf, outR, outI);
  }
}

// Round 2
// 99.836 us; speedup vs baseline: 1.7143x; 1.7143x over previous
//
#include <hip/hip_runtime.h>
#include <hip/hip_bf16.h>
#include <stdint.h>

#define XLEN   262144
#define NT     513
#define NTP    528               // padded frames per batch (8*528 = 4224 = 66*64)
#define NB     8
#define NCOL   (NB * NTP)        // 4224 fused columns
#define NK     1088              // direct freq rows k = 0..1087 (17 tiles of 64)
#define NFFT   2048
#define OUTKT  (2048 * NT)

typedef __attribute__((ext_vector_type(8))) short short8;
typedef __attribute__((ext_vector_type(4))) float f32x4;

__device__ __forceinline__ short cvt_bf16(float f) {
  return __builtin_bit_cast(short, (__bf16)f);
}

__device__ __forceinline__ void gload16(const short* g, const short* l) {
  __builtin_amdgcn_global_load_lds(
      (const __attribute__((address_space(1))) void*)g,
      (__attribute__((address_space(3))) void*)l, 16, 0, 0);
}

// ---------------- prep: fp32 weights (rows 0..1087) -> bf16, natural row-major ----------------
__global__ __launch_bounds__(256) void conv_w_kernel(const float* __restrict__ wsin,
                                                     const float* __restrict__ wcos,
                                                     short* __restrict__ wc,
                                                     short* __restrict__ ws) {
  const int row = blockIdx.x;
  const int c = threadIdx.x * 8;
  const float* src = (blockIdx.y ? wsin : wcos) + (size_t)row * NFFT + c;
  short* dst = (blockIdx.y ? ws : wc) + (size_t)row * NFFT + c;
  f32x4 a = *(const f32x4*)src;
  f32x4 b = *(const f32x4*)(src + 4);
  short8 o;
#pragma unroll
  for (int j = 0; j < 4; ++j) { o[j] = cvt_bf16(a[j]); o[4 + j] = cvt_bf16(b[j]); }
  *(short8*)dst = o;
}

// ---------------- prep: reflect-padded frames -> bf16 [4224][2048], pad cols zeroed ----------------
__global__ __launch_bounds__(256) void conv_frames_kernel(const float* __restrict__ x,
                                                          short* __restrict__ fr) {
  const int j = blockIdx.x;             // fused column 0..4223
  const int b = j / NTP;
  const int t = j - b * NTP;
  const int c = threadIdx.x * 8;
  short8 o;
  if (t >= NT) {
#pragma unroll
    for (int k = 0; k < 8; ++k) o[k] = 0;
  } else {
    const float* xb = x + (size_t)b * XLEN;
    const int base = t * 512 + c - 1024;
    float v[8];
    if (base >= 0 && base + 7 < XLEN) {
      *(f32x4*)(v)     = *(const f32x4*)(xb + base);
      *(f32x4*)(v + 4) = *(const f32x4*)(xb + base + 4);
    } else {
#pragma unroll
      for (int k = 0; k < 8; ++k) {
        int m = base + k;
        m = (m < 0) ? -m : m;
        m = (m >= XLEN) ? (2 * XLEN - 2 - m) : m;
        v[k] = xb[m];
      }
    }
#pragma unroll
    for (int k = 0; k < 8; ++k) o[k] = cvt_bf16(v[k]);
  }
  *(short8*)&fr[(size_t)j * NFFT + c] = o;
}

// ---------------- main GEMM ----------------
// C[k,j] (real via wcos, imag via wsin), k in [0,1088), j in [0,4224).
// BM=64 (k), BN=64 (j), BK=64; 4 waves in 2x2, each 32x32 per matrix.
// LDS: [A_cos | A_sin | B_frames], each 64x64 bf16 linear rows of 64 shorts;
// 16B-chunk index XOR-swizzled with (row&7) on BOTH the global source (staging)
// and the ds_read side (same involution; global_load_lds writes linearly).
template <bool WS>
__global__ __launch_bounds__(256, 4) void dft_gemm_kernel(
    const float* __restrict__ x,
    const float* __restrict__ wsin_f,
    const float* __restrict__ wcos_f,
    const short* __restrict__ wc_bf,
    const short* __restrict__ ws_bf,
    const short* __restrict__ fr_bf,
    float* __restrict__ outR,
    float* __restrict__ outI) {
  __shared__ short lds[3 * 64 * 64];  // 24 KiB

  const int tid  = threadIdx.x;
  const int lane = tid & 63;
  const int wid  = tid >> 6;
  const int k0   = blockIdx.x * 64;
  const int j0   = blockIdx.y * 64;
  const int wr   = (wid >> 1) * 32;
  const int wc   = (wid & 1) * 32;

  f32x4 accR[2][2], accI[2][2];
#pragma unroll
  for (int m = 0; m < 2; ++m)
#pragma unroll
    for (int n = 0; n < 2; ++n) { accR[m][n] = (f32x4)0.0f; accI[m][n] = (f32x4)0.0f; }

  const int fr_r = lane & 15;
  const int fk   = (lane >> 4) * 8;
  const int srow = lane >> 3;                  // 0..7 within 8-row chunk
  const int scol = ((lane & 7) ^ srow) * 8;    // swizzled source chunk (shorts)

  for (int n0 = 0; n0 < NFFT; n0 += 64) {
    if (n0) __syncthreads();
    // ---- stage 3 x 64x64 bf16 tiles; 6 wave-instructions (1 KiB each) per wave ----
#pragma unroll
    for (int i = 0; i < 6; ++i) {
      const int q   = wid * 6 + i;   // 0..23, wave-uniform
      const int reg = q >> 3;        // 0=wcos 1=wsin 2=frames
      const int rq  = q & 7;         // 8-row chunk within tile
      const int row = rq * 8 + srow;
      if (WS) {
        const short* src =
            (reg == 0) ? wc_bf + (size_t)(k0 + row) * NFFT + n0 + scol
          : (reg == 1) ? ws_bf + (size_t)(k0 + row) * NFFT + n0 + scol
                       : fr_bf + (size_t)(j0 + row) * NFFT + n0 + scol;
        gload16(src, &lds[reg * 4096 + rq * 512]);
      } else {
        short8 v;
        if (reg < 2) {
          const float* s = (reg == 0 ? wcos_f : wsin_f) + (size_t)(k0 + row) * NFFT + n0 + scol;
          f32x4 u0 = *(const f32x4*)s, u1 = *(const f32x4*)(s + 4);
#pragma unroll
          for (int jx = 0; jx < 4; ++jx) { v[jx] = cvt_bf16(u0[jx]); v[4 + jx] = cvt_bf16(u1[jx]); }
        } else {
          const int jj = j0 + row;
          const int b = jj / NTP, t = jj - b * NTP;
          if (t < NT) {
            const float* xb = x + (size_t)b * XLEN;
            const int base = t * 512 + n0 + scol - 1024;
            float fv[8];
            if (base >= 0 && base + 7 < XLEN) {
              *(f32x4*)(fv)     = *(const f32x4*)(xb + base);
              *(f32x4*)(fv + 4) = *(const f32x4*)(xb + base + 4);
            } else {
#pragma unroll
              for (int k = 0; k < 8; ++k) {
                int m = base + k;
                m = (m < 0) ? -m : m;
                m = (m >= XLEN) ? (2 * XLEN - 2 - m) : m;
                fv[k] = xb[m];
              }
            }
#pragma unroll
            for (int k = 0; k < 8; ++k) v[k] = cvt_bf16(fv[k]);
          } else {
#pragma unroll
            for (int k = 0; k < 8; ++k) v[k] = 0;
          }
        }
        *(short8*)&lds[reg * 4096 + rq * 512 + lane * 8] = v;
      }
    }
    __syncthreads();
    // ---- compute: 2 k-substeps; per wave 6 ds_read_b128 + 8 MFMA per substep ----
#pragma unroll
    for (int ks = 0; ks < 2; ++ks) {
      const int kb = ks * 32 + fk;  // short col, multiple of 8
      short8 a_c[2], a_s[2], b_f[2];
#pragma unroll
      for (int m = 0; m < 2; ++m) {
        const int r = wr + m * 16 + fr_r;
        const int off = (r << 6) + ((((kb >> 3) ^ (r & 7)) << 3));
        a_c[m] = *(const short8*)&lds[off];
        a_s[m] = *(const short8*)&lds[4096 + off];
      }
#pragma unroll
      for (int n = 0; n < 2; ++n) {
        const int r = wc + n * 16 + fr_r;
        const int off = (r << 6) + ((((kb >> 3) ^ (r & 7)) << 3));
        b_f[n] = *(const short8*)&lds[8192 + off];
      }
#pragma unroll
      for (int m = 0; m < 2; ++m)
#pragma unroll
        for (int n = 0; n < 2; ++n) {
          accR[m][n] = __builtin_amdgcn_mfma_f32_16x16x32_bf16(a_c[m], b_f[n], accR[m][n], 0, 0, 0);
          accI[m][n] = __builtin_amdgcn_mfma_f32_16x16x32_bf16(a_s[m], b_f[n], accI[m][n], 0, 0, 0);
        }
    }
  }

  // ---- epilogue: direct rows k (0..1087) + Hermitian mirror to 2048-k for k in [1,960] ----
#pragma unroll
  for (int m = 0; m < 2; ++m) {
#pragma unroll
    for (int n = 0; n < 2; ++n) {
      const int k = k0 + wr + m * 16 + (lane >> 4) * 4;
      const int j = j0 + wc + n * 16 + (lane & 15);
      const int b = j / NTP;
      const int t = j - b * NTP;
      if (t < NT) {
#pragma unroll
        for (int r = 0; r < 4; ++r) {
          const int kk = k + r;
          const float vr = accR[m][n][r];
          const float vi = accI[m][n][r];
          const size_t base = (size_t)b * OUTKT + (size_t)kk * NT + t;
          outR[base] = vr;
          outI[base] = -vi;
          if (kk >= 1 && kk <= 960) {
            const size_t mb = (size_t)b * OUTKT + (size_t)(2048 - kk) * NT + t;
            outR[mb] = vr;   // cos mirror: equal
            outI[mb] = vi;   // -(-imag) : sin mirror negated
          }
        }
      }
    }
  }
}

extern "C" void kernel_launch(void* const* d_in, const int* in_sizes, int n_in,
                              void* d_out, int out_size, void* d_ws, size_t ws_size,
                              hipStream_t stream) {
  const float* x    = (const float*)d_in[0];
  const float* wsin = (const float*)d_in[1];
  const float* wcos = (const float*)d_in[2];
  float* outR = (float*)d_out;
  float* outI = outR + (size_t)NB * OUTKT;

  short* wc_bf = (short*)d_ws;
  short* ws_bf = wc_bf + (size_t)NK * NFFT;
  short* fr_bf = ws_bf + (size_t)NK * NFFT;
  const size_t ws_need = ((size_t)2 * NK + NCOL) * NFFT * sizeof(short);  // ~26.2 MB

  dim3 grid(NK / 64, NCOL / 64, 1);  // 17 x 66 = 1122 blocks
  if (ws_size >= ws_need) {
    conv_w_kernel<<<dim3(NK, 2), 256, 0, stream>>>(wsin, wcos, wc_bf, ws_bf);
    conv_frames_kernel<<<NCOL, 256, 0, stream>>>(x, fr_bf);
    dft_gemm_kernel<true><<<grid, 256, 0, stream>>>(x, wsin, wcos, wc_bf, ws_bf, fr_bf, outR, outI);
  } else {
    dft_gemm_kernel<false><<<grid, 256, 0, stream>>>(x, wsin, wcos, wc_bf, ws_bf, fr_bf, outR, outI);
  }
}